// Round 6
// baseline (238.153 us; speedup 1.0000x reference)
//
#include <hip/hip_runtime.h>
#include <hip/hip_bf16.h>

#define BQ 2
#define SEQ 2048
#define DM 1024
#define NH 16
#define DHEAD 64

typedef unsigned short u16;
typedef unsigned int u32;
typedef __attribute__((ext_vector_type(8))) short short8;   // 8 bf16 = 4 VGPRs
typedef __attribute__((ext_vector_type(4))) float f32x4;    // MFMA C/D frag

__device__ __forceinline__ u16 f2b(float f) {
    unsigned u = __builtin_bit_cast(unsigned, f);
    unsigned r = u + 0x7fffu + ((u >> 16) & 1u);   // RNE
    return (u16)(r >> 16);
}

__device__ __forceinline__ void gld_lds16(const void* g, void* l) {
    __builtin_amdgcn_global_load_lds(
        (const __attribute__((address_space(1))) void*)g,
        (__attribute__((address_space(3))) void*)l, 16, 0, 0);
}

// ---------------- prep kernels ----------------

__global__ __launch_bounds__(256) void cvt_x_kernel(const float* __restrict__ x,
                                                    u16* __restrict__ xb) {
    int i = blockIdx.x * 256 + threadIdx.x;       // one float4 per thread
    float4 v = ((const float4*)x)[i];
    ushort4 o;
    o.x = f2b(v.x); o.y = f2b(v.y); o.z = f2b(v.z); o.w = f2b(v.w);
    ((ushort4*)xb)[i] = o;
}

// fused 4-weight transpose: W[k][d] f32 -> wt[wsel*1024 + d][k] bf16
__global__ __launch_bounds__(256) void pack_w4(
        const float* __restrict__ W0, const float* __restrict__ W1,
        const float* __restrict__ W2, const float* __restrict__ W3,
        u16* __restrict__ wt) {
    __shared__ u16 Ws[64][68];
    const float* W = (blockIdx.z == 0) ? W0 : (blockIdx.z == 1) ? W1
                   : (blockIdx.z == 2) ? W2 : W3;
    const int k0 = blockIdx.x * 64, d0 = blockIdx.y * 64;
    const int t = threadIdx.x;
    const int lrow = t >> 4, lcol = (t & 15) * 4;
    #pragma unroll
    for (int i = 0; i < 4; i++) {
        float4 v = *(const float4*)(W + (size_t)(k0 + lrow + i * 16) * DM + d0 + lcol);
        Ws[lrow + i * 16][lcol + 0] = f2b(v.x);
        Ws[lrow + i * 16][lcol + 1] = f2b(v.y);
        Ws[lrow + i * 16][lcol + 2] = f2b(v.z);
        Ws[lrow + i * 16][lcol + 3] = f2b(v.w);
    }
    __syncthreads();
    const int dl = t >> 2, kq = (t & 3) * 16;
    uint4 o1, o2;
    o1.x = (u32)Ws[kq + 0][dl]  | ((u32)Ws[kq + 1][dl]  << 16);
    o1.y = (u32)Ws[kq + 2][dl]  | ((u32)Ws[kq + 3][dl]  << 16);
    o1.z = (u32)Ws[kq + 4][dl]  | ((u32)Ws[kq + 5][dl]  << 16);
    o1.w = (u32)Ws[kq + 6][dl]  | ((u32)Ws[kq + 7][dl]  << 16);
    o2.x = (u32)Ws[kq + 8][dl]  | ((u32)Ws[kq + 9][dl]  << 16);
    o2.y = (u32)Ws[kq + 10][dl] | ((u32)Ws[kq + 11][dl] << 16);
    o2.z = (u32)Ws[kq + 12][dl] | ((u32)Ws[kq + 13][dl] << 16);
    o2.w = (u32)Ws[kq + 14][dl] | ((u32)Ws[kq + 15][dl] << 16);
    u16* dst = wt + (size_t)(blockIdx.z * DM + d0 + dl) * DM + k0 + kq;
    *(uint4*)(dst) = o1;
    *(uint4*)(dst + 8) = o2;
}

__global__ __launch_bounds__(256) void pack_bias_kernel(const float* __restrict__ b0,
                                                        const float* __restrict__ b1,
                                                        const float* __restrict__ b2,
                                                        const float* __restrict__ b3,
                                                        float* __restrict__ bias) {
    int i = blockIdx.x * 256 + threadIdx.x;       // 0..4095
    const float* s = (i < 1024) ? b0 : (i < 2048) ? b1 : (i < 3072) ? b2 : b3;
    bias[i] = s[i & 1023];
}

__global__ __launch_bounds__(256) void calc_len_kernel(const int* __restrict__ mask,
                                                       int* __restrict__ lengths) {
    __shared__ int cnt[BQ];
    if (threadIdx.x < BQ) cnt[threadIdx.x] = 0;
    __syncthreads();
    for (int b = 0; b < BQ; b++) {
        int c = 0;
        for (int s = threadIdx.x; s < SEQ; s += 256)
            c += (mask[b * SEQ + s] != 0) ? 1 : 0;
        atomicAdd(&cnt[b], c);
    }
    __syncthreads();
    if (threadIdx.x < BQ) lengths[threadIdx.x] = cnt[threadIdx.x];
}

// ---------------- fused QKVR GEMM (m97 pattern: global_load_lds) ----------------
// Y[m][n] = sum_k xb[m][k] * wt[n][k] + bias[n];  M=4096, N=4096, K=1024

__global__ __launch_bounds__(256) void gemm_qkvr(
        const u16* __restrict__ xb, const u16* __restrict__ wt,
        const float* __restrict__ bias,
        u16* __restrict__ qbuf, u16* __restrict__ kbuf, u16* __restrict__ vbuf,
        float* __restrict__ out) {
    __shared__ __align__(16) u16 As[128 * 32];
    __shared__ __align__(16) u16 Bs[128 * 32];
    const int tid = threadIdx.x;
    const int wid = tid >> 6, lane = tid & 63;
    const int lr = lane & 15, lg = lane >> 4;
    const int bm = blockIdx.x, bn = blockIdx.y;
    const int wm = (wid >> 1) * 64, wn = (wid & 1) * 64;

    const int crow = lane >> 2, ccol = (lane & 3) * 8;
    const u16* agp0 = xb + (size_t)(bm * 128 + (wid * 2 + 0) * 16 + crow) * DM + ccol;
    const u16* agp1 = xb + (size_t)(bm * 128 + (wid * 2 + 1) * 16 + crow) * DM + ccol;
    const u16* bgp0 = wt + (size_t)(bn * 128 + (wid * 2 + 0) * 16 + crow) * DM + ccol;
    const u16* bgp1 = wt + (size_t)(bn * 128 + (wid * 2 + 1) * 16 + crow) * DM + ccol;
    u16* al0 = As + (wid * 2 + 0) * 512;
    u16* al1 = As + (wid * 2 + 1) * 512;
    u16* bl0 = Bs + (wid * 2 + 0) * 512;
    u16* bl1 = Bs + (wid * 2 + 1) * 512;

    f32x4 acc[4][4] = {};

    for (int kk = 0; kk < DM; kk += 32) {
        gld_lds16(agp0 + kk, al0);
        gld_lds16(agp1 + kk, al1);
        gld_lds16(bgp0 + kk, bl0);
        gld_lds16(bgp1 + kk, bl1);
        __syncthreads();
        short8 af[4], bfr[4];
        #pragma unroll
        for (int mt = 0; mt < 4; mt++)
            af[mt] = *(const short8*)(As + (wm + mt * 16 + lr) * 32 + lg * 8);
        #pragma unroll
        for (int nt = 0; nt < 4; nt++)
            bfr[nt] = *(const short8*)(Bs + (wn + nt * 16 + lr) * 32 + lg * 8);
        #pragma unroll
        for (int mt = 0; mt < 4; mt++)
            #pragma unroll
            for (int nt = 0; nt < 4; nt++)
                acc[mt][nt] = __builtin_amdgcn_mfma_f32_16x16x32_bf16(
                        af[mt], bfr[nt], acc[mt][nt], 0, 0, 0);
        __syncthreads();
    }

    #pragma unroll
    for (int nt = 0; nt < 4; nt++) {
        int n = bn * 128 + wn + nt * 16 + lr;
        int which = n >> 10, d = n & 1023;
        float bv_ = bias[n];
        #pragma unroll
        for (int mt = 0; mt < 4; mt++) {
            #pragma unroll
            for (int r = 0; r < 4; r++) {
                int m = bm * 128 + wm + mt * 16 + lg * 4 + r;   // = b*SEQ + s
                float y = acc[mt][nt][r] + bv_;
                if (which == 3) {
                    out[(size_t)m * DM + d] = y;
                } else {
                    int h = d >> 6, dh = d & 63;
                    int b = m >> 11, s = m & (SEQ - 1);
                    size_t idx = ((size_t)(b * NH + h) * SEQ + s) * DHEAD + dh;
                    u16 hv = f2b(y);
                    if (which == 0) qbuf[idx] = hv;
                    else if (which == 1) kbuf[idx] = hv;
                    else vbuf[idx] = hv;
                }
            }
        }
    }
}

// ---------------- flash attention v6: round-3 body, 2 waves/block ----------------
// EXACT round-3 (passing) per-wave algorithm. Only change: two independent
// waves per 128-thread block with private LDS halves; waves take complementary
// q-tiles (15-z, z) so block durations are balanced. No __syncthreads.

__global__ __launch_bounds__(128, 3) void attn_kernel(
        const u16* __restrict__ qbuf, const u16* __restrict__ kbuf,
        const u16* __restrict__ vbuf, const int* __restrict__ lengths,
        float* __restrict__ out) {
    __shared__ __align__(16) u32 lds[2][64 * 32 + 32 * 32];

    const int wid = threadIdx.x >> 6;
    const int bh = blockIdx.x;                       // 32 (b*16+h)
    const int slice = blockIdx.y;                    // 4 q-slices of 32 rows
    const int zz = blockIdx.z;                       // 8
    const int qt = wid ? zz : 15 - zz;               // complementary pair
    const int b = bh >> 4, h = bh & 15;
    const int len = lengths[b];
    const int qw = qt * 128 + slice * 32;            // wave's first q row
    if (qw >= len) return;

    u32* Vt = &lds[wid][0];                          // [64 d][32 key-pair words]
    u32* Pl = &lds[wid][2048];                       // [32 q][32 key-pair words]

    const int lane = threadIdx.x & 63;
    const int lr = lane & 15, lg = lane >> 4;
    const int swz = (lr & 7) << 2;

    const u16* qp = qbuf + (size_t)bh * SEQ * DHEAD;
    const u16* kp = kbuf + (size_t)bh * SEQ * DHEAD;
    const u16* vp = vbuf + (size_t)bh * SEQ * DHEAD;

    // Q B-frags in registers for the whole kernel
    short8 bq[2][2];
    #pragma unroll
    for (int ntq = 0; ntq < 2; ntq++)
        #pragma unroll
        for (int ks = 0; ks < 2; ks++)
            bq[ntq][ks] = *(const short8*)(qp + (size_t)(qw + ntq * 16 + lr) * DHEAD + ks * 32 + lg * 8);

    f32x4 oacc[4][2] = {};
    float mrow[2] = {-3.0e38f, -3.0e38f};
    float lsum[2] = {0.0f, 0.0f};

    const int nkt = (qw >> 6) + 1;                   // exactly the tiles this wave needs
    const int vk = (lane & 31) * 2;                  // key pair owned in V staging
    const int vd0 = (lane >> 5) * 8;                 // d group 0 or 8
    const float SC = 0.125f * 1.44269504f;           // 1/sqrt(64) * log2(e)

    // prologue: V(0) global->reg
    uint4 vreg[8];
    #pragma unroll
    for (int c = 0; c < 4; c++) {
        const u16* vrow = vp + (size_t)vk * DHEAD + vd0 + c * 16;
        vreg[2 * c]     = *(const uint4*)vrow;
        vreg[2 * c + 1] = *(const uint4*)(vrow + DHEAD);
    }

    for (int kt = 0; kt < nkt; kt++) {
        const int kbase = kt * 64;

        // Vt(kt) reg->LDS (transposed pairs, swizzled)
        #pragma unroll
        for (int c = 0; c < 4; c++) {
            union { uint4 v; u16 sv[8]; } ua, ub;
            ua.v = vreg[2 * c]; ub.v = vreg[2 * c + 1];
            int d = vd0 + c * 16;
            #pragma unroll
            for (int j = 0; j < 8; j++) {
                u32 w = (u32)ua.sv[j] | ((u32)ub.sv[j] << 16);
                Vt[(d + j) * 32 + ((vk >> 1) ^ (j << 2))] = w;
            }
        }
        // async-stage: issue V(kt+1) loads now; latency hides under QK+softmax+PV
        if (kt + 1 < nkt) {
            #pragma unroll
            for (int c = 0; c < 4; c++) {
                const u16* vrow = vp + (size_t)(kbase + 64 + vk) * DHEAD + vd0 + c * 16;
                vreg[2 * c]     = *(const uint4*)vrow;
                vreg[2 * c + 1] = *(const uint4*)(vrow + DHEAD);
            }
        }

        // QK^T swapped: A = K rows (keys), B = Q rows -> D[key][q]
        short8 ak[4][2];
        #pragma unroll
        for (int mtk = 0; mtk < 4; mtk++)
            #pragma unroll
            for (int ks = 0; ks < 2; ks++)
                ak[mtk][ks] = *(const short8*)(kp + (size_t)(kbase + mtk * 16 + lr) * DHEAD + ks * 32 + lg * 8);
        f32x4 sc[4][2] = {};
        #pragma unroll
        for (int mtk = 0; mtk < 4; mtk++)
            #pragma unroll
            for (int ks = 0; ks < 2; ks++)
                #pragma unroll
                for (int ntq = 0; ntq < 2; ntq++)
                    sc[mtk][ntq] = __builtin_amdgcn_mfma_f32_16x16x32_bf16(
                            ak[mtk][ks], bq[ntq][ks], sc[mtk][ntq], 0, 0, 0);

        // scale (exp2 domain) + causal mask (last tile only)
        const bool maskful = (kbase + 63 > qw);
        if (maskful) {
            #pragma unroll
            for (int mtk = 0; mtk < 4; mtk++) {
                int keyb = kbase + mtk * 16 + lg * 4;
                #pragma unroll
                for (int ntq = 0; ntq < 2; ntq++) {
                    int qq = qw + ntq * 16 + lr;
                    #pragma unroll
                    for (int r = 0; r < 4; r++)
                        sc[mtk][ntq][r] = (keyb + r > qq) ? -3.0e38f
                                                          : sc[mtk][ntq][r] * SC;
                }
            }
        } else {
            #pragma unroll
            for (int mtk = 0; mtk < 4; mtk++)
                #pragma unroll
                for (int ntq = 0; ntq < 2; ntq++)
                    #pragma unroll
                    for (int r = 0; r < 4; r++)
                        sc[mtk][ntq][r] *= SC;
        }

        // online softmax: 16 in-lane + 2 shuffles (lanes hold disjoint keys)
        float scl[2];
        #pragma unroll
        for (int ntq = 0; ntq < 2; ntq++) {
            float mx = sc[0][ntq][0];
            #pragma unroll
            for (int mtk = 0; mtk < 4; mtk++)
                #pragma unroll
                for (int r = 0; r < 4; r++)
                    mx = fmaxf(mx, sc[mtk][ntq][r]);
            mx = fmaxf(mx, __shfl_xor(mx, 16, 64));
            mx = fmaxf(mx, __shfl_xor(mx, 32, 64));
            float mnew = fmaxf(mrow[ntq], mx);
            float sq = exp2f(mrow[ntq] - mnew);
            mrow[ntq] = mnew;
            float ps = 0.0f;
            #pragma unroll
            for (int mtk = 0; mtk < 4; mtk++)
                #pragma unroll
                for (int r = 0; r < 4; r++) {
                    float p = exp2f(sc[mtk][ntq][r] - mnew);
                    sc[mtk][ntq][r] = p;
                    ps += p;
                }
            ps += __shfl_xor(ps, 16, 64);
            ps += __shfl_xor(ps, 32, 64);
            lsum[ntq] = lsum[ntq] * sq + ps;
            scl[ntq] = sq;
        }
        // rescale O (in-lane: O^T col q = ntq*16+lr)
        #pragma unroll
        for (int mtd = 0; mtd < 4; mtd++)
            #pragma unroll
            for (int ntq = 0; ntq < 2; ntq++)
                #pragma unroll
                for (int r = 0; r < 4; r++)
                    oacc[mtd][ntq][r] *= scl[ntq];

        // P -> LDS (bf16 pairs, swizzled)
        #pragma unroll
        for (int ntq = 0; ntq < 2; ntq++) {
            int rowbase = (ntq * 16 + lr) * 32;
            #pragma unroll
            for (int mtk = 0; mtk < 4; mtk++)
                #pragma unroll
                for (int i = 0; i < 2; i++) {
                    u32 w = (u32)f2b(sc[mtk][ntq][2 * i])
                          | ((u32)f2b(sc[mtk][ntq][2 * i + 1]) << 16);
                    Pl[rowbase + ((mtk * 8 + lg * 2 + i) ^ swz)] = w;
                }
        }

        // PV swapped: A = Vt rows (d), B = P rows (q) -> D[d][q] = O^T
        #pragma unroll
        for (int ks = 0; ks < 2; ks++) {
            int wv = (ks * 16 + lg * 4) ^ swz;
            short8 bp0 = *(const short8*)&Pl[(lr) * 32 + wv];
            short8 bp1 = *(const short8*)&Pl[(16 + lr) * 32 + wv];
            #pragma unroll
            for (int mtd = 0; mtd < 4; mtd++) {
                short8 av = *(const short8*)&Vt[(mtd * 16 + lr) * 32 + wv];
                oacc[mtd][0] = __builtin_amdgcn_mfma_f32_16x16x32_bf16(av, bp0, oacc[mtd][0], 0, 0, 0);
                oacc[mtd][1] = __builtin_amdgcn_mfma_f32_16x16x32_bf16(av, bp1, oacc[mtd][1], 0, 0, 0);
            }
        }
    }

    // epilogue: O^T[d][q]: d = mtd*16+lg*4+r, q = ntq*16+lr (in-lane lsum)
    #pragma unroll
    for (int ntq = 0; ntq < 2; ntq++) {
        int q = qw + ntq * 16 + lr;
        if (q < len) {
            float inv = 1.0f / lsum[ntq];
            float* orow = out + (size_t)(b * SEQ + q) * DM + h * DHEAD;
            #pragma unroll
            for (int mtd = 0; mtd < 4; mtd++)
                #pragma unroll
                for (int r = 0; r < 4; r++)
                    orow[mtd * 16 + lg * 4 + r] += oacc[mtd][ntq][r] * inv;
        }
    }
}

// ---------------- launch ----------------

extern "C" void kernel_launch(void* const* d_in, const int* in_sizes, int n_in,
                              void* d_out, int out_size, void* d_ws, size_t ws_size,
                              hipStream_t stream) {
    const float* x  = (const float*)d_in[0];
    const int*  mask = (const int*)d_in[1];
    const float* Wq = (const float*)d_in[2];
    const float* bq = (const float*)d_in[3];
    const float* Wk = (const float*)d_in[4];
    const float* bk = (const float*)d_in[5];
    const float* Wv = (const float*)d_in[6];
    const float* bv = (const float*)d_in[7];
    const float* Wr = (const float*)d_in[8];
    const float* br = (const float*)d_in[9];
    float* out = (float*)d_out;

    char* ws = (char*)d_ws;
    size_t off = 0;
    auto alloc = [&](size_t bytes) {
        size_t o = off; off = (off + bytes + 255) & ~(size_t)255; return o;
    };
    u16* xb   = (u16*)(ws + alloc((size_t)BQ * SEQ * DM * 2));
    u16* wt   = (u16*)(ws + alloc((size_t)4 * DM * DM * 2));
    float* bias = (float*)(ws + alloc(4 * DM * 4));
    u16* qbuf = (u16*)(ws + alloc((size_t)BQ * NH * SEQ * DHEAD * 2));
    u16* kbuf = (u16*)(ws + alloc((size_t)BQ * NH * SEQ * DHEAD * 2));
    u16* vbuf = (u16*)(ws + alloc((size_t)BQ * NH * SEQ * DHEAD * 2));
    int* lens = (int*)(ws + alloc(256));

    hipLaunchKernelGGL(cvt_x_kernel, dim3((BQ * SEQ * DM) / 4 / 256), dim3(256), 0, stream, x, xb);
    hipLaunchKernelGGL(pack_w4, dim3(16, 16, 4), dim3(256), 0, stream, Wq, Wk, Wv, Wr, wt);
    hipLaunchKernelGGL(pack_bias_kernel, dim3(16), dim3(256), 0, stream, bq, bk, bv, br, bias);
    hipLaunchKernelGGL(calc_len_kernel, dim3(1), dim3(256), 0, stream, mask, lens);
    hipLaunchKernelGGL(gemm_qkvr, dim3(32, 32), dim3(256), 0, stream,
                       xb, wt, bias, qbuf, kbuf, vbuf, out);
    hipLaunchKernelGGL(attn_kernel, dim3(BQ * NH, 4, 8), dim3(128), 0, stream,
                       qbuf, kbuf, vbuf, lens, out);
}

// Round 7
// 195.055 us; speedup vs baseline: 1.2209x; 1.2209x over previous
//
#include <hip/hip_runtime.h>
#include <hip/hip_bf16.h>

#define BQ 2
#define SEQ 2048
#define DM 1024
#define NH 16
#define DHEAD 64

typedef unsigned short u16;
typedef unsigned int u32;
typedef __attribute__((ext_vector_type(8))) short short8;   // 8 bf16 = 4 VGPRs
typedef __attribute__((ext_vector_type(4))) float f32x4;    // MFMA C/D frag

__device__ __forceinline__ u16 f2b(float f) {
    unsigned u = __builtin_bit_cast(unsigned, f);
    unsigned r = u + 0x7fffu + ((u >> 16) & 1u);   // RNE
    return (u16)(r >> 16);
}

__device__ __forceinline__ void gld_lds16(const void* g, void* l) {
    __builtin_amdgcn_global_load_lds(
        (const __attribute__((address_space(1))) void*)g,
        (__attribute__((address_space(3))) void*)l, 16, 0, 0);
}

// ---------------- prep kernels ----------------

__global__ __launch_bounds__(256) void cvt_x_kernel(const float* __restrict__ x,
                                                    u16* __restrict__ xb) {
    int i = blockIdx.x * 256 + threadIdx.x;       // one float4 per thread
    float4 v = ((const float4*)x)[i];
    ushort4 o;
    o.x = f2b(v.x); o.y = f2b(v.y); o.z = f2b(v.z); o.w = f2b(v.w);
    ((ushort4*)xb)[i] = o;
}

// fused 4-weight transpose: W[k][d] f32 -> wt[wsel*1024 + d][k] bf16
__global__ __launch_bounds__(256) void pack_w4(
        const float* __restrict__ W0, const float* __restrict__ W1,
        const float* __restrict__ W2, const float* __restrict__ W3,
        u16* __restrict__ wt) {
    __shared__ u16 Ws[64][68];
    const float* W = (blockIdx.z == 0) ? W0 : (blockIdx.z == 1) ? W1
                   : (blockIdx.z == 2) ? W2 : W3;
    const int k0 = blockIdx.x * 64, d0 = blockIdx.y * 64;
    const int t = threadIdx.x;
    const int lrow = t >> 4, lcol = (t & 15) * 4;
    #pragma unroll
    for (int i = 0; i < 4; i++) {
        float4 v = *(const float4*)(W + (size_t)(k0 + lrow + i * 16) * DM + d0 + lcol);
        Ws[lrow + i * 16][lcol + 0] = f2b(v.x);
        Ws[lrow + i * 16][lcol + 1] = f2b(v.y);
        Ws[lrow + i * 16][lcol + 2] = f2b(v.z);
        Ws[lrow + i * 16][lcol + 3] = f2b(v.w);
    }
    __syncthreads();
    const int dl = t >> 2, kq = (t & 3) * 16;
    uint4 o1, o2;
    o1.x = (u32)Ws[kq + 0][dl]  | ((u32)Ws[kq + 1][dl]  << 16);
    o1.y = (u32)Ws[kq + 2][dl]  | ((u32)Ws[kq + 3][dl]  << 16);
    o1.z = (u32)Ws[kq + 4][dl]  | ((u32)Ws[kq + 5][dl]  << 16);
    o1.w = (u32)Ws[kq + 6][dl]  | ((u32)Ws[kq + 7][dl]  << 16);
    o2.x = (u32)Ws[kq + 8][dl]  | ((u32)Ws[kq + 9][dl]  << 16);
    o2.y = (u32)Ws[kq + 10][dl] | ((u32)Ws[kq + 11][dl] << 16);
    o2.z = (u32)Ws[kq + 12][dl] | ((u32)Ws[kq + 13][dl] << 16);
    o2.w = (u32)Ws[kq + 14][dl] | ((u32)Ws[kq + 15][dl] << 16);
    u16* dst = wt + (size_t)(blockIdx.z * DM + d0 + dl) * DM + k0 + kq;
    *(uint4*)(dst) = o1;
    *(uint4*)(dst + 8) = o2;
}

__global__ __launch_bounds__(256) void pack_bias_kernel(const float* __restrict__ b0,
                                                        const float* __restrict__ b1,
                                                        const float* __restrict__ b2,
                                                        const float* __restrict__ b3,
                                                        float* __restrict__ bias) {
    int i = blockIdx.x * 256 + threadIdx.x;       // 0..4095
    const float* s = (i < 1024) ? b0 : (i < 2048) ? b1 : (i < 3072) ? b2 : b3;
    bias[i] = s[i & 1023];
}

__global__ __launch_bounds__(256) void calc_len_kernel(const int* __restrict__ mask,
                                                       int* __restrict__ lengths) {
    __shared__ int cnt[BQ];
    if (threadIdx.x < BQ) cnt[threadIdx.x] = 0;
    __syncthreads();
    for (int b = 0; b < BQ; b++) {
        int c = 0;
        for (int s = threadIdx.x; s < SEQ; s += 256)
            c += (mask[b * SEQ + s] != 0) ? 1 : 0;
        atomicAdd(&cnt[b], c);
    }
    __syncthreads();
    if (threadIdx.x < BQ) lengths[threadIdx.x] = cnt[threadIdx.x];
}

// ---------------- fused QKVR GEMM (m97 pattern: global_load_lds) ----------------
// Y[m][n] = sum_k xb[m][k] * wt[n][k] + bias[n];  M=4096, N=4096, K=1024

__global__ __launch_bounds__(256) void gemm_qkvr(
        const u16* __restrict__ xb, const u16* __restrict__ wt,
        const float* __restrict__ bias,
        u16* __restrict__ qbuf, u16* __restrict__ kbuf, u16* __restrict__ vbuf,
        float* __restrict__ out) {
    __shared__ __align__(16) u16 As[128 * 32];
    __shared__ __align__(16) u16 Bs[128 * 32];
    const int tid = threadIdx.x;
    const int wid = tid >> 6, lane = tid & 63;
    const int lr = lane & 15, lg = lane >> 4;
    const int bm = blockIdx.x, bn = blockIdx.y;
    const int wm = (wid >> 1) * 64, wn = (wid & 1) * 64;

    const int crow = lane >> 2, ccol = (lane & 3) * 8;
    const u16* agp0 = xb + (size_t)(bm * 128 + (wid * 2 + 0) * 16 + crow) * DM + ccol;
    const u16* agp1 = xb + (size_t)(bm * 128 + (wid * 2 + 1) * 16 + crow) * DM + ccol;
    const u16* bgp0 = wt + (size_t)(bn * 128 + (wid * 2 + 0) * 16 + crow) * DM + ccol;
    const u16* bgp1 = wt + (size_t)(bn * 128 + (wid * 2 + 1) * 16 + crow) * DM + ccol;
    u16* al0 = As + (wid * 2 + 0) * 512;
    u16* al1 = As + (wid * 2 + 1) * 512;
    u16* bl0 = Bs + (wid * 2 + 0) * 512;
    u16* bl1 = Bs + (wid * 2 + 1) * 512;

    f32x4 acc[4][4] = {};

    for (int kk = 0; kk < DM; kk += 32) {
        gld_lds16(agp0 + kk, al0);
        gld_lds16(agp1 + kk, al1);
        gld_lds16(bgp0 + kk, bl0);
        gld_lds16(bgp1 + kk, bl1);
        __syncthreads();
        short8 af[4], bfr[4];
        #pragma unroll
        for (int mt = 0; mt < 4; mt++)
            af[mt] = *(const short8*)(As + (wm + mt * 16 + lr) * 32 + lg * 8);
        #pragma unroll
        for (int nt = 0; nt < 4; nt++)
            bfr[nt] = *(const short8*)(Bs + (wn + nt * 16 + lr) * 32 + lg * 8);
        #pragma unroll
        for (int mt = 0; mt < 4; mt++)
            #pragma unroll
            for (int nt = 0; nt < 4; nt++)
                acc[mt][nt] = __builtin_amdgcn_mfma_f32_16x16x32_bf16(
                        af[mt], bfr[nt], acc[mt][nt], 0, 0, 0);
        __syncthreads();
    }

    #pragma unroll
    for (int nt = 0; nt < 4; nt++) {
        int n = bn * 128 + wn + nt * 16 + lr;
        int which = n >> 10, d = n & 1023;
        float bv_ = bias[n];
        #pragma unroll
        for (int mt = 0; mt < 4; mt++) {
            #pragma unroll
            for (int r = 0; r < 4; r++) {
                int m = bm * 128 + wm + mt * 16 + lg * 4 + r;   // = b*SEQ + s
                float y = acc[mt][nt][r] + bv_;
                if (which == 3) {
                    out[(size_t)m * DM + d] = y;
                } else {
                    int h = d >> 6, dh = d & 63;
                    int b = m >> 11, s = m & (SEQ - 1);
                    size_t idx = ((size_t)(b * NH + h) * SEQ + s) * DHEAD + dh;
                    u16 hv = f2b(y);
                    if (which == 0) qbuf[idx] = hv;
                    else if (which == 1) kbuf[idx] = hv;
                    else vbuf[idx] = hv;
                }
            }
        }
    }
}

// ---------------- flash attention v7: round-6 body, unconstrained VGPRs ----------------
// EXACT round-6 (passing) algorithm. Only change: __launch_bounds__(128) with
// NO min-waves arg — rounds 3/6 used (.,3) which squeezed the allocator to 84
// VGPRs (< ~120 live state) and caused scratch spills (WRITE_SIZE 15->50MB).
// LDS (24KB/block) already caps occupancy at 6 blocks/CU = 3 waves/SIMD, so
// releasing the VGPR cap costs nothing.

__global__ __launch_bounds__(128) void attn_kernel(
        const u16* __restrict__ qbuf, const u16* __restrict__ kbuf,
        const u16* __restrict__ vbuf, const int* __restrict__ lengths,
        float* __restrict__ out) {
    __shared__ __align__(16) u32 lds[2][64 * 32 + 32 * 32];

    const int wid = threadIdx.x >> 6;
    const int bh = blockIdx.x;                       // 32 (b*16+h)
    const int slice = blockIdx.y;                    // 4 q-slices of 32 rows
    const int zz = blockIdx.z;                       // 8
    const int qt = wid ? zz : 15 - zz;               // complementary pair
    const int b = bh >> 4, h = bh & 15;
    const int len = lengths[b];
    const int qw = qt * 128 + slice * 32;            // wave's first q row
    if (qw >= len) return;

    u32* Vt = &lds[wid][0];                          // [64 d][32 key-pair words]
    u32* Pl = &lds[wid][2048];                       // [32 q][32 key-pair words]

    const int lane = threadIdx.x & 63;
    const int lr = lane & 15, lg = lane >> 4;
    const int swz = (lr & 7) << 2;

    const u16* qp = qbuf + (size_t)bh * SEQ * DHEAD;
    const u16* kp = kbuf + (size_t)bh * SEQ * DHEAD;
    const u16* vp = vbuf + (size_t)bh * SEQ * DHEAD;

    // Q B-frags in registers for the whole kernel
    short8 bq[2][2];
    #pragma unroll
    for (int ntq = 0; ntq < 2; ntq++)
        #pragma unroll
        for (int ks = 0; ks < 2; ks++)
            bq[ntq][ks] = *(const short8*)(qp + (size_t)(qw + ntq * 16 + lr) * DHEAD + ks * 32 + lg * 8);

    f32x4 oacc[4][2] = {};
    float mrow[2] = {-3.0e38f, -3.0e38f};
    float lsum[2] = {0.0f, 0.0f};

    const int nkt = (qw >> 6) + 1;                   // exactly the tiles this wave needs
    const int vk = (lane & 31) * 2;                  // key pair owned in V staging
    const int vd0 = (lane >> 5) * 8;                 // d group 0 or 8
    const float SC = 0.125f * 1.44269504f;           // 1/sqrt(64) * log2(e)

    // prologue: V(0) global->reg
    uint4 vreg[8];
    #pragma unroll
    for (int c = 0; c < 4; c++) {
        const u16* vrow = vp + (size_t)vk * DHEAD + vd0 + c * 16;
        vreg[2 * c]     = *(const uint4*)vrow;
        vreg[2 * c + 1] = *(const uint4*)(vrow + DHEAD);
    }

    for (int kt = 0; kt < nkt; kt++) {
        const int kbase = kt * 64;

        // Vt(kt) reg->LDS (transposed pairs, swizzled)
        #pragma unroll
        for (int c = 0; c < 4; c++) {
            union { uint4 v; u16 sv[8]; } ua, ub;
            ua.v = vreg[2 * c]; ub.v = vreg[2 * c + 1];
            int d = vd0 + c * 16;
            #pragma unroll
            for (int j = 0; j < 8; j++) {
                u32 w = (u32)ua.sv[j] | ((u32)ub.sv[j] << 16);
                Vt[(d + j) * 32 + ((vk >> 1) ^ (j << 2))] = w;
            }
        }
        // async-stage: issue V(kt+1) loads now; latency hides under QK+softmax+PV
        if (kt + 1 < nkt) {
            #pragma unroll
            for (int c = 0; c < 4; c++) {
                const u16* vrow = vp + (size_t)(kbase + 64 + vk) * DHEAD + vd0 + c * 16;
                vreg[2 * c]     = *(const uint4*)vrow;
                vreg[2 * c + 1] = *(const uint4*)(vrow + DHEAD);
            }
        }

        // QK^T swapped: A = K rows (keys), B = Q rows -> D[key][q]
        short8 ak[4][2];
        #pragma unroll
        for (int mtk = 0; mtk < 4; mtk++)
            #pragma unroll
            for (int ks = 0; ks < 2; ks++)
                ak[mtk][ks] = *(const short8*)(kp + (size_t)(kbase + mtk * 16 + lr) * DHEAD + ks * 32 + lg * 8);
        f32x4 sc[4][2] = {};
        #pragma unroll
        for (int mtk = 0; mtk < 4; mtk++)
            #pragma unroll
            for (int ks = 0; ks < 2; ks++)
                #pragma unroll
                for (int ntq = 0; ntq < 2; ntq++)
                    sc[mtk][ntq] = __builtin_amdgcn_mfma_f32_16x16x32_bf16(
                            ak[mtk][ks], bq[ntq][ks], sc[mtk][ntq], 0, 0, 0);

        // scale (exp2 domain) + causal mask (last tile only)
        const bool maskful = (kbase + 63 > qw);
        if (maskful) {
            #pragma unroll
            for (int mtk = 0; mtk < 4; mtk++) {
                int keyb = kbase + mtk * 16 + lg * 4;
                #pragma unroll
                for (int ntq = 0; ntq < 2; ntq++) {
                    int qq = qw + ntq * 16 + lr;
                    #pragma unroll
                    for (int r = 0; r < 4; r++)
                        sc[mtk][ntq][r] = (keyb + r > qq) ? -3.0e38f
                                                          : sc[mtk][ntq][r] * SC;
                }
            }
        } else {
            #pragma unroll
            for (int mtk = 0; mtk < 4; mtk++)
                #pragma unroll
                for (int ntq = 0; ntq < 2; ntq++)
                    #pragma unroll
                    for (int r = 0; r < 4; r++)
                        sc[mtk][ntq][r] *= SC;
        }

        // online softmax: 16 in-lane + 2 shuffles (lanes hold disjoint keys)
        float scl[2];
        #pragma unroll
        for (int ntq = 0; ntq < 2; ntq++) {
            float mx = sc[0][ntq][0];
            #pragma unroll
            for (int mtk = 0; mtk < 4; mtk++)
                #pragma unroll
                for (int r = 0; r < 4; r++)
                    mx = fmaxf(mx, sc[mtk][ntq][r]);
            mx = fmaxf(mx, __shfl_xor(mx, 16, 64));
            mx = fmaxf(mx, __shfl_xor(mx, 32, 64));
            float mnew = fmaxf(mrow[ntq], mx);
            float sq = exp2f(mrow[ntq] - mnew);
            mrow[ntq] = mnew;
            float ps = 0.0f;
            #pragma unroll
            for (int mtk = 0; mtk < 4; mtk++)
                #pragma unroll
                for (int r = 0; r < 4; r++) {
                    float p = exp2f(sc[mtk][ntq][r] - mnew);
                    sc[mtk][ntq][r] = p;
                    ps += p;
                }
            ps += __shfl_xor(ps, 16, 64);
            ps += __shfl_xor(ps, 32, 64);
            lsum[ntq] = lsum[ntq] * sq + ps;
            scl[ntq] = sq;
        }
        // rescale O (in-lane: O^T col q = ntq*16+lr)
        #pragma unroll
        for (int mtd = 0; mtd < 4; mtd++)
            #pragma unroll
            for (int ntq = 0; ntq < 2; ntq++)
                #pragma unroll
                for (int r = 0; r < 4; r++)
                    oacc[mtd][ntq][r] *= scl[ntq];

        // P -> LDS (bf16 pairs, swizzled)
        #pragma unroll
        for (int ntq = 0; ntq < 2; ntq++) {
            int rowbase = (ntq * 16 + lr) * 32;
            #pragma unroll
            for (int mtk = 0; mtk < 4; mtk++)
                #pragma unroll
                for (int i = 0; i < 2; i++) {
                    u32 w = (u32)f2b(sc[mtk][ntq][2 * i])
                          | ((u32)f2b(sc[mtk][ntq][2 * i + 1]) << 16);
                    Pl[rowbase + ((mtk * 8 + lg * 2 + i) ^ swz)] = w;
                }
        }

        // PV swapped: A = Vt rows (d), B = P rows (q) -> D[d][q] = O^T
        #pragma unroll
        for (int ks = 0; ks < 2; ks++) {
            int wv = (ks * 16 + lg * 4) ^ swz;
            short8 bp0 = *(const short8*)&Pl[(lr) * 32 + wv];
            short8 bp1 = *(const short8*)&Pl[(16 + lr) * 32 + wv];
            #pragma unroll
            for (int mtd = 0; mtd < 4; mtd++) {
                short8 av = *(const short8*)&Vt[(mtd * 16 + lr) * 32 + wv];
                oacc[mtd][0] = __builtin_amdgcn_mfma_f32_16x16x32_bf16(av, bp0, oacc[mtd][0], 0, 0, 0);
                oacc[mtd][1] = __builtin_amdgcn_mfma_f32_16x16x32_bf16(av, bp1, oacc[mtd][1], 0, 0, 0);
            }
        }
    }

    // epilogue: O^T[d][q]: d = mtd*16+lg*4+r, q = ntq*16+lr (in-lane lsum)
    #pragma unroll
    for (int ntq = 0; ntq < 2; ntq++) {
        int q = qw + ntq * 16 + lr;
        if (q < len) {
            float inv = 1.0f / lsum[ntq];
            float* orow = out + (size_t)(b * SEQ + q) * DM + h * DHEAD;
            #pragma unroll
            for (int mtd = 0; mtd < 4; mtd++)
                #pragma unroll
                for (int r = 0; r < 4; r++)
                    orow[mtd * 16 + lg * 4 + r] += oacc[mtd][ntq][r] * inv;
        }
    }
}

// ---------------- launch ----------------

extern "C" void kernel_launch(void* const* d_in, const int* in_sizes, int n_in,
                              void* d_out, int out_size, void* d_ws, size_t ws_size,
                              hipStream_t stream) {
    const float* x  = (const float*)d_in[0];
    const int*  mask = (const int*)d_in[1];
    const float* Wq = (const float*)d_in[2];
    const float* bq = (const float*)d_in[3];
    const float* Wk = (const float*)d_in[4];
    const float* bk = (const float*)d_in[5];
    const float* Wv = (const float*)d_in[6];
    const float* bv = (const float*)d_in[7];
    const float* Wr = (const float*)d_in[8];
    const float* br = (const float*)d_in[9];
    float* out = (float*)d_out;

    char* ws = (char*)d_ws;
    size_t off = 0;
    auto alloc = [&](size_t bytes) {
        size_t o = off; off = (off + bytes + 255) & ~(size_t)255; return o;
    };
    u16* xb   = (u16*)(ws + alloc((size_t)BQ * SEQ * DM * 2));
    u16* wt   = (u16*)(ws + alloc((size_t)4 * DM * DM * 2));
    float* bias = (float*)(ws + alloc(4 * DM * 4));
    u16* qbuf = (u16*)(ws + alloc((size_t)BQ * NH * SEQ * DHEAD * 2));
    u16* kbuf = (u16*)(ws + alloc((size_t)BQ * NH * SEQ * DHEAD * 2));
    u16* vbuf = (u16*)(ws + alloc((size_t)BQ * NH * SEQ * DHEAD * 2));
    int* lens = (int*)(ws + alloc(256));

    hipLaunchKernelGGL(cvt_x_kernel, dim3((BQ * SEQ * DM) / 4 / 256), dim3(256), 0, stream, x, xb);
    hipLaunchKernelGGL(pack_w4, dim3(16, 16, 4), dim3(256), 0, stream, Wq, Wk, Wv, Wr, wt);
    hipLaunchKernelGGL(pack_bias_kernel, dim3(16), dim3(256), 0, stream, bq, bk, bv, br, bias);
    hipLaunchKernelGGL(calc_len_kernel, dim3(1), dim3(256), 0, stream, mask, lens);
    hipLaunchKernelGGL(gemm_qkvr, dim3(32, 32), dim3(256), 0, stream,
                       xb, wt, bias, qbuf, kbuf, vbuf, out);
    hipLaunchKernelGGL(attn_kernel, dim3(BQ * NH, 4, 8), dim3(128), 0, stream,
                       qbuf, kbuf, vbuf, lens, out);
}

// Round 10
// 183.219 us; speedup vs baseline: 1.2998x; 1.0646x over previous
//
#include <hip/hip_runtime.h>
#include <hip/hip_bf16.h>

#define BQ 2
#define SEQ 2048
#define DM 1024
#define NH 16
#define DHEAD 64

typedef unsigned short u16;
typedef unsigned int u32;
typedef __attribute__((ext_vector_type(8))) short short8;   // 8 bf16 = 4 VGPRs
typedef __attribute__((ext_vector_type(4))) float f32x4;    // MFMA C/D frag

__device__ __forceinline__ u16 f2b(float f) {
    unsigned u = __builtin_bit_cast(unsigned, f);
    unsigned r = u + 0x7fffu + ((u >> 16) & 1u);   // RNE
    return (u16)(r >> 16);
}

__device__ __forceinline__ void gld_lds16(const void* g, void* l) {
    __builtin_amdgcn_global_load_lds(
        (const __attribute__((address_space(1))) void*)g,
        (__attribute__((address_space(3))) void*)l, 16, 0, 0);
}

// ---------------- prep kernels ----------------

__global__ __launch_bounds__(256) void cvt_x_kernel(const float* __restrict__ x,
                                                    u16* __restrict__ xb) {
    int i = blockIdx.x * 256 + threadIdx.x;       // one float4 per thread
    float4 v = ((const float4*)x)[i];
    ushort4 o;
    o.x = f2b(v.x); o.y = f2b(v.y); o.z = f2b(v.z); o.w = f2b(v.w);
    ((ushort4*)xb)[i] = o;
}

// fused 4-weight transpose: W[k][d] f32 -> wt[wsel*1024 + d][k] bf16
__global__ __launch_bounds__(256) void pack_w4(
        const float* __restrict__ W0, const float* __restrict__ W1,
        const float* __restrict__ W2, const float* __restrict__ W3,
        u16* __restrict__ wt) {
    __shared__ u16 Ws[64][68];
    const float* W = (blockIdx.z == 0) ? W0 : (blockIdx.z == 1) ? W1
                   : (blockIdx.z == 2) ? W2 : W3;
    const int k0 = blockIdx.x * 64, d0 = blockIdx.y * 64;
    const int t = threadIdx.x;
    const int lrow = t >> 4, lcol = (t & 15) * 4;
    #pragma unroll
    for (int i = 0; i < 4; i++) {
        float4 v = *(const float4*)(W + (size_t)(k0 + lrow + i * 16) * DM + d0 + lcol);
        Ws[lrow + i * 16][lcol + 0] = f2b(v.x);
        Ws[lrow + i * 16][lcol + 1] = f2b(v.y);
        Ws[lrow + i * 16][lcol + 2] = f2b(v.z);
        Ws[lrow + i * 16][lcol + 3] = f2b(v.w);
    }
    __syncthreads();
    const int dl = t >> 2, kq = (t & 3) * 16;
    uint4 o1, o2;
    o1.x = (u32)Ws[kq + 0][dl]  | ((u32)Ws[kq + 1][dl]  << 16);
    o1.y = (u32)Ws[kq + 2][dl]  | ((u32)Ws[kq + 3][dl]  << 16);
    o1.z = (u32)Ws[kq + 4][dl]  | ((u32)Ws[kq + 5][dl]  << 16);
    o1.w = (u32)Ws[kq + 6][dl]  | ((u32)Ws[kq + 7][dl]  << 16);
    o2.x = (u32)Ws[kq + 8][dl]  | ((u32)Ws[kq + 9][dl]  << 16);
    o2.y = (u32)Ws[kq + 10][dl] | ((u32)Ws[kq + 11][dl] << 16);
    o2.z = (u32)Ws[kq + 12][dl] | ((u32)Ws[kq + 13][dl] << 16);
    o2.w = (u32)Ws[kq + 14][dl] | ((u32)Ws[kq + 15][dl] << 16);
    u16* dst = wt + (size_t)(blockIdx.z * DM + d0 + dl) * DM + k0 + kq;
    *(uint4*)(dst) = o1;
    *(uint4*)(dst + 8) = o2;
}

__global__ __launch_bounds__(256) void pack_bias_kernel(const float* __restrict__ b0,
                                                        const float* __restrict__ b1,
                                                        const float* __restrict__ b2,
                                                        const float* __restrict__ b3,
                                                        float* __restrict__ bias) {
    int i = blockIdx.x * 256 + threadIdx.x;       // 0..4095
    const float* s = (i < 1024) ? b0 : (i < 2048) ? b1 : (i < 3072) ? b2 : b3;
    bias[i] = s[i & 1023];
}

__global__ __launch_bounds__(256) void calc_len_kernel(const int* __restrict__ mask,
                                                       int* __restrict__ lengths) {
    __shared__ int cnt[BQ];
    if (threadIdx.x < BQ) cnt[threadIdx.x] = 0;
    __syncthreads();
    for (int b = 0; b < BQ; b++) {
        int c = 0;
        for (int s = threadIdx.x; s < SEQ; s += 256)
            c += (mask[b * SEQ + s] != 0) ? 1 : 0;
        atomicAdd(&cnt[b], c);
    }
    __syncthreads();
    if (threadIdx.x < BQ) lengths[threadIdx.x] = cnt[threadIdx.x];
}

// ---------------- fused QKVR GEMM (m97 pattern: global_load_lds) ----------------
// Y[m][n] = sum_k xb[m][k] * wt[n][k] + bias[n];  M=4096, N=4096, K=1024

__global__ __launch_bounds__(256) void gemm_qkvr(
        const u16* __restrict__ xb, const u16* __restrict__ wt,
        const float* __restrict__ bias,
        u16* __restrict__ qbuf, u16* __restrict__ kbuf, u16* __restrict__ vbuf,
        float* __restrict__ out) {
    __shared__ __align__(16) u16 As[128 * 32];
    __shared__ __align__(16) u16 Bs[128 * 32];
    const int tid = threadIdx.x;
    const int wid = tid >> 6, lane = tid & 63;
    const int lr = lane & 15, lg = lane >> 4;
    const int bm = blockIdx.x, bn = blockIdx.y;
    const int wm = (wid >> 1) * 64, wn = (wid & 1) * 64;

    const int crow = lane >> 2, ccol = (lane & 3) * 8;
    const u16* agp0 = xb + (size_t)(bm * 128 + (wid * 2 + 0) * 16 + crow) * DM + ccol;
    const u16* agp1 = xb + (size_t)(bm * 128 + (wid * 2 + 1) * 16 + crow) * DM + ccol;
    const u16* bgp0 = wt + (size_t)(bn * 128 + (wid * 2 + 0) * 16 + crow) * DM + ccol;
    const u16* bgp1 = wt + (size_t)(bn * 128 + (wid * 2 + 1) * 16 + crow) * DM + ccol;
    u16* al0 = As + (wid * 2 + 0) * 512;
    u16* al1 = As + (wid * 2 + 1) * 512;
    u16* bl0 = Bs + (wid * 2 + 0) * 512;
    u16* bl1 = Bs + (wid * 2 + 1) * 512;

    f32x4 acc[4][4] = {};

    for (int kk = 0; kk < DM; kk += 32) {
        gld_lds16(agp0 + kk, al0);
        gld_lds16(agp1 + kk, al1);
        gld_lds16(bgp0 + kk, bl0);
        gld_lds16(bgp1 + kk, bl1);
        __syncthreads();
        short8 af[4], bfr[4];
        #pragma unroll
        for (int mt = 0; mt < 4; mt++)
            af[mt] = *(const short8*)(As + (wm + mt * 16 + lr) * 32 + lg * 8);
        #pragma unroll
        for (int nt = 0; nt < 4; nt++)
            bfr[nt] = *(const short8*)(Bs + (wn + nt * 16 + lr) * 32 + lg * 8);
        #pragma unroll
        for (int mt = 0; mt < 4; mt++)
            #pragma unroll
            for (int nt = 0; nt < 4; nt++)
                acc[mt][nt] = __builtin_amdgcn_mfma_f32_16x16x32_bf16(
                        af[mt], bfr[nt], acc[mt][nt], 0, 0, 0);
        __syncthreads();
    }

    #pragma unroll
    for (int nt = 0; nt < 4; nt++) {
        int n = bn * 128 + wn + nt * 16 + lr;
        int which = n >> 10, d = n & 1023;
        float bv_ = bias[n];
        #pragma unroll
        for (int mt = 0; mt < 4; mt++) {
            #pragma unroll
            for (int r = 0; r < 4; r++) {
                int m = bm * 128 + wm + mt * 16 + lg * 4 + r;   // = b*SEQ + s
                float y = acc[mt][nt][r] + bv_;
                if (which == 3) {
                    out[(size_t)m * DM + d] = y;
                } else {
                    int h = d >> 6, dh = d & 63;
                    int b = m >> 11, s = m & (SEQ - 1);
                    size_t idx = ((size_t)(b * NH + h) * SEQ + s) * DHEAD + dh;
                    u16 hv = f2b(y);
                    if (which == 0) qbuf[idx] = hv;
                    else if (which == 1) kbuf[idx] = hv;
                    else vbuf[idx] = hv;
                }
            }
        }
    }
}

// ---------------- flash attention v9: K-split + round-7-proven inner math ----------------
// One 256-thread block per (bh, 32-q-row slice); 4 waves split K-tiles
// round-robin (kt = wid, wid+4, ...). Inner math = round-7 verbatim:
// swapped QK (intrinsic), scale+mask, always-rescale softmax, P->LDS swizzled,
// PV via 16x16x32 intrinsic from Vt+Pl. Partials merged after one barrier.

__global__ __launch_bounds__(256) void attn_kernel(
        const u16* __restrict__ qbuf, const u16* __restrict__ kbuf,
        const u16* __restrict__ vbuf, const int* __restrict__ lengths,
        float* __restrict__ out) {
    __shared__ __align__(16) u32 lds[4][3072];        // per wave: Vt[0..2047], Pl[2048..3071]
    __shared__ float msh[4][32], lsh[4][32];

    const int p = blockIdx.x;                         // 2048 blocks
    const int xcd = p & 7, pj = p >> 3;
    const int bh = xcd * 4 + (pj & 3);                // 4 heads per XCD
    const int slice = pj >> 2;                        // 0..63
    const int b = bh >> 4, h = bh & 15;
    const int len = lengths[b];
    const int qw = slice * 32;
    if (qw >= len) return;

    const int tid = threadIdx.x, wid = tid >> 6, lane = tid & 63;
    const int lr = lane & 15, lg = lane >> 4;
    const int swz = (lr & 7) << 2;

    u32* Vt = &lds[wid][0];                           // [64 d][32 key-pair words]
    u32* Pl = &lds[wid][2048];                        // [32 q][32 key-pair words]

    const u16* qp = qbuf + (size_t)bh * SEQ * DHEAD;
    const u16* kp = kbuf + (size_t)bh * SEQ * DHEAD;
    const u16* vp = vbuf + (size_t)bh * SEQ * DHEAD;

    // Q B-frags in registers
    short8 bq[2][2];
    #pragma unroll
    for (int ntq = 0; ntq < 2; ntq++)
        #pragma unroll
        for (int ks = 0; ks < 2; ks++)
            bq[ntq][ks] = *(const short8*)(qp + (size_t)(qw + ntq * 16 + lr) * DHEAD + ks * 32 + lg * 8);

    f32x4 oacc[4][2] = {};
    float mrow[2] = {-3.0e38f, -3.0e38f};
    float lsum[2] = {0.0f, 0.0f};

    const int last = (qw + 31) >> 6;                  // last K-tile index
    const int vk = (lane & 31) * 2;                   // key pair owned in V staging
    const int vd0 = (lane >> 5) * 8;                  // d group 0 or 8
    const float SC = 0.125f * 1.44269504f;            // 1/sqrt(64) * log2(e)

    // prologue: V(first own tile) global->reg
    uint4 vreg[8];
    if (wid <= last) {
        #pragma unroll
        for (int c = 0; c < 4; c++) {
            const u16* vrow = vp + (size_t)(wid * 64 + vk) * DHEAD + vd0 + c * 16;
            vreg[2 * c]     = *(const uint4*)vrow;
            vreg[2 * c + 1] = *(const uint4*)(vrow + DHEAD);
        }
    }

    for (int kt = wid; kt <= last; kt += 4) {
        const int kbase = kt * 64;

        // Vt(kt) reg->LDS (transposed pairs, swizzled word ^ ((d&7)<<2))
        #pragma unroll
        for (int c = 0; c < 4; c++) {
            union { uint4 v; u16 sv[8]; } ua, ub;
            ua.v = vreg[2 * c]; ub.v = vreg[2 * c + 1];
            int d = vd0 + c * 16;
            #pragma unroll
            for (int j = 0; j < 8; j++) {
                u32 w = (u32)ua.sv[j] | ((u32)ub.sv[j] << 16);
                Vt[(d + j) * 32 + ((vk >> 1) ^ (j << 2))] = w;
            }
        }
        // prefetch V(kt+4) global->reg
        if (kt + 4 <= last) {
            #pragma unroll
            for (int c = 0; c < 4; c++) {
                const u16* vrow = vp + (size_t)((kt + 4) * 64 + vk) * DHEAD + vd0 + c * 16;
                vreg[2 * c]     = *(const uint4*)vrow;
                vreg[2 * c + 1] = *(const uint4*)(vrow + DHEAD);
            }
        }

        // QK^T swapped: A = K rows (keys), B = Q rows -> D[key][q]
        short8 ak[4][2];
        #pragma unroll
        for (int mtk = 0; mtk < 4; mtk++)
            #pragma unroll
            for (int ks = 0; ks < 2; ks++)
                ak[mtk][ks] = *(const short8*)(kp + (size_t)(kbase + mtk * 16 + lr) * DHEAD + ks * 32 + lg * 8);
        f32x4 sc[4][2] = {};
        #pragma unroll
        for (int mtk = 0; mtk < 4; mtk++)
            #pragma unroll
            for (int ks = 0; ks < 2; ks++)
                #pragma unroll
                for (int ntq = 0; ntq < 2; ntq++)
                    sc[mtk][ntq] = __builtin_amdgcn_mfma_f32_16x16x32_bf16(
                            ak[mtk][ks], bq[ntq][ks], sc[mtk][ntq], 0, 0, 0);

        // scale (exp2 domain) + causal mask (round-7 verbatim)
        const bool maskful = (kbase + 63 > qw);
        if (maskful) {
            #pragma unroll
            for (int mtk = 0; mtk < 4; mtk++) {
                int keyb = kbase + mtk * 16 + lg * 4;
                #pragma unroll
                for (int ntq = 0; ntq < 2; ntq++) {
                    int qq = qw + ntq * 16 + lr;
                    #pragma unroll
                    for (int r = 0; r < 4; r++)
                        sc[mtk][ntq][r] = (keyb + r > qq) ? -3.0e38f
                                                          : sc[mtk][ntq][r] * SC;
                }
            }
        } else {
            #pragma unroll
            for (int mtk = 0; mtk < 4; mtk++)
                #pragma unroll
                for (int ntq = 0; ntq < 2; ntq++)
                    #pragma unroll
                    for (int r = 0; r < 4; r++)
                        sc[mtk][ntq][r] *= SC;
        }

        // online softmax (always-rescale): 16 in-lane + 2 shuffles per group
        float scl[2];
        #pragma unroll
        for (int ntq = 0; ntq < 2; ntq++) {
            float mx = sc[0][ntq][0];
            #pragma unroll
            for (int mtk = 0; mtk < 4; mtk++)
                #pragma unroll
                for (int r = 0; r < 4; r++)
                    mx = fmaxf(mx, sc[mtk][ntq][r]);
            mx = fmaxf(mx, __shfl_xor(mx, 16, 64));
            mx = fmaxf(mx, __shfl_xor(mx, 32, 64));
            float mnew = fmaxf(mrow[ntq], mx);
            float sq = exp2f(mrow[ntq] - mnew);
            mrow[ntq] = mnew;
            float ps = 0.0f;
            #pragma unroll
            for (int mtk = 0; mtk < 4; mtk++)
                #pragma unroll
                for (int r = 0; r < 4; r++) {
                    float pp = exp2f(sc[mtk][ntq][r] - mnew);
                    sc[mtk][ntq][r] = pp;
                    ps += pp;
                }
            ps += __shfl_xor(ps, 16, 64);
            ps += __shfl_xor(ps, 32, 64);
            lsum[ntq] = lsum[ntq] * sq + ps;
            scl[ntq] = sq;
        }
        #pragma unroll
        for (int mtd = 0; mtd < 4; mtd++)
            #pragma unroll
            for (int ntq = 0; ntq < 2; ntq++)
                #pragma unroll
                for (int r = 0; r < 4; r++)
                    oacc[mtd][ntq][r] *= scl[ntq];

        // P -> LDS (bf16 pairs, swizzled) — round-7 verbatim
        #pragma unroll
        for (int ntq = 0; ntq < 2; ntq++) {
            int rowbase = (ntq * 16 + lr) * 32;
            #pragma unroll
            for (int mtk = 0; mtk < 4; mtk++)
                #pragma unroll
                for (int i = 0; i < 2; i++) {
                    u32 w = (u32)f2b(sc[mtk][ntq][2 * i])
                          | ((u32)f2b(sc[mtk][ntq][2 * i + 1]) << 16);
                    Pl[rowbase + ((mtk * 8 + lg * 2 + i) ^ swz)] = w;
                }
        }

        // PV swapped: A = Vt rows (d), B = P rows (q) -> D[d][q] = O^T
        #pragma unroll
        for (int ks = 0; ks < 2; ks++) {
            int wv = (ks * 16 + lg * 4) ^ swz;
            short8 bp0 = *(const short8*)&Pl[(lr) * 32 + wv];
            short8 bp1 = *(const short8*)&Pl[(16 + lr) * 32 + wv];
            #pragma unroll
            for (int mtd = 0; mtd < 4; mtd++) {
                short8 av = *(const short8*)&Vt[(mtd * 16 + lr) * 32 + wv];
                oacc[mtd][0] = __builtin_amdgcn_mfma_f32_16x16x32_bf16(av, bp0, oacc[mtd][0], 0, 0, 0);
                oacc[mtd][1] = __builtin_amdgcn_mfma_f32_16x16x32_bf16(av, bp1, oacc[mtd][1], 0, 0, 0);
            }
        }
    }

    // write partial: O^T numerator as [q][64 d] f32 into own slot (Vt dead)
    {
        float* fs = (float*)&lds[wid][0];
        #pragma unroll
        for (int mtd = 0; mtd < 4; mtd++)
            #pragma unroll
            for (int ntq = 0; ntq < 2; ntq++)
                #pragma unroll
                for (int r = 0; r < 4; r++)
                    fs[(ntq * 16 + lr) * 64 + mtd * 16 + lg * 4 + r] = oacc[mtd][ntq][r];
        if (lg == 0) {
            msh[wid][lr]      = mrow[0];
            msh[wid][16 + lr] = mrow[1];
            lsh[wid][lr]      = lsum[0];
            lsh[wid][16 + lr] = lsum[1];
        }
    }
    __syncthreads();

    // merge 4 partials and add to out (residual already there)
    {
        const int q = tid >> 3, dblk = (tid & 7) * 8;
        if (qw + q < len) {
            float m0 = msh[0][q], m1 = msh[1][q], m2 = msh[2][q], m3 = msh[3][q];
            float M = fmaxf(fmaxf(m0, m1), fmaxf(m2, m3));
            float f0 = exp2f(m0 - M), f1 = exp2f(m1 - M);
            float f2 = exp2f(m2 - M), f3 = exp2f(m3 - M);
            float L = f0 * lsh[0][q] + f1 * lsh[1][q] + f2 * lsh[2][q] + f3 * lsh[3][q];
            float inv = 1.0f / L;
            const float* s0 = (const float*)&lds[0][0] + q * 64 + dblk;
            float* orow = out + ((size_t)b * SEQ + qw + q) * DM + h * DHEAD + dblk;
            #pragma unroll
            for (int i = 0; i < 8; i++) {
                float v = f0 * s0[i] + f1 * s0[3072 + i]
                        + f2 * s0[6144 + i] + f3 * s0[9216 + i];
                orow[i] += v * inv;
            }
        }
    }
}

// ---------------- launch ----------------

extern "C" void kernel_launch(void* const* d_in, const int* in_sizes, int n_in,
                              void* d_out, int out_size, void* d_ws, size_t ws_size,
                              hipStream_t stream) {
    const float* x  = (const float*)d_in[0];
    const int*  mask = (const int*)d_in[1];
    const float* Wq = (const float*)d_in[2];
    const float* bq = (const float*)d_in[3];
    const float* Wk = (const float*)d_in[4];
    const float* bk = (const float*)d_in[5];
    const float* Wv = (const float*)d_in[6];
    const float* bv = (const float*)d_in[7];
    const float* Wr = (const float*)d_in[8];
    const float* br = (const float*)d_in[9];
    float* out = (float*)d_out;

    char* ws = (char*)d_ws;
    size_t off = 0;
    auto alloc = [&](size_t bytes) {
        size_t o = off; off = (off + bytes + 255) & ~(size_t)255; return o;
    };
    u16* xb   = (u16*)(ws + alloc((size_t)BQ * SEQ * DM * 2));
    u16* wt   = (u16*)(ws + alloc((size_t)4 * DM * DM * 2));
    float* bias = (float*)(ws + alloc(4 * DM * 4));
    u16* qbuf = (u16*)(ws + alloc((size_t)BQ * NH * SEQ * DHEAD * 2));
    u16* kbuf = (u16*)(ws + alloc((size_t)BQ * NH * SEQ * DHEAD * 2));
    u16* vbuf = (u16*)(ws + alloc((size_t)BQ * NH * SEQ * DHEAD * 2));
    int* lens = (int*)(ws + alloc(256));

    hipLaunchKernelGGL(cvt_x_kernel, dim3((BQ * SEQ * DM) / 4 / 256), dim3(256), 0, stream, x, xb);
    hipLaunchKernelGGL(pack_w4, dim3(16, 16, 4), dim3(256), 0, stream, Wq, Wk, Wv, Wr, wt);
    hipLaunchKernelGGL(pack_bias_kernel, dim3(16), dim3(256), 0, stream, bq, bk, bv, br, bias);
    hipLaunchKernelGGL(calc_len_kernel, dim3(1), dim3(256), 0, stream, mask, lens);
    hipLaunchKernelGGL(gemm_qkvr, dim3(32, 32), dim3(256), 0, stream,
                       xb, wt, bias, qbuf, kbuf, vbuf, out);
    hipLaunchKernelGGL(attn_kernel, dim3(BQ * NH * (SEQ / 32)), dim3(256), 0, stream,
                       qbuf, kbuf, vbuf, lens, out);
}